// Round 1
// baseline (1283.636 us; speedup 1.0000x reference)
//
#include <hip/hip_runtime.h>
#include <math.h>

#define BATCH 256
#define NNODE 256
#define FIN   128
#define HID   48
#define DOUT  97

// ---------- rowsum -> dinv = 1/sqrt(rowsum(A)+2) ----------
__global__ __launch_bounds__(256) void k_dinv(const float* __restrict__ A,
                                              float* __restrict__ dinv,
                                              int n, int rows) {
  int wid  = (blockIdx.x * blockDim.x + threadIdx.x) >> 6;
  int lane = threadIdx.x & 63;
  if (wid >= rows) return;
  const float* row = A + (size_t)wid * n;
  float s = 0.f;
  for (int j = lane; j < n; j += 64) s += row[j];
  #pragma unroll
  for (int o = 32; o > 0; o >>= 1) s += __shfl_down(s, o);
  if (lane == 0) dinv[wid] = 1.0f / sqrtf(s + 2.0f);
}

// ---------- XW = H @ W  (rows x K) @ (K x F) ----------
__global__ __launch_bounds__(256) void k_xw(const float* __restrict__ H,
                                            const float* __restrict__ W,
                                            float* __restrict__ XW,
                                            int rowsTotal, int K, int F) {
  __shared__ float sW[6144];   // max 128*48 or 48*97
  __shared__ float sH[1024];   // 8 rows * K (K<=128)
  int t = threadIdx.x;
  for (int i = t; i < K * F; i += 256) sW[i] = W[i];
  long row0 = (long)blockIdx.x * 8;
  int nrows = min(8, rowsTotal - (int)row0);
  for (int i = t; i < nrows * K; i += 256) sH[i] = H[row0 * K + i];
  __syncthreads();
  for (int idx = t; idx < nrows * F; idx += 256) {
    int r = idx / F, f = idx - r * F;
    const float* hr = &sH[r * K];
    float acc = 0.f;
    for (int k2 = 0; k2 < K; k2++) acc += hr[k2] * sW[k2 * F + f];
    XW[(row0 + r) * F + f] = acc;
  }
}

// ---------- out = relu?( D^{1/2}-normalized (A+2I) @ XW + bias ) ----------
// out[b,i,f] = d_i*(sum_j A_ij d_j xw_jf) + 2 d_i^2 xw_if + bias_f
__global__ __launch_bounds__(256) void k_anxw(const float* __restrict__ A,
                                              const float* __restrict__ dinv,
                                              const float* __restrict__ xw,
                                              const float* __restrict__ bias,
                                              float* __restrict__ out,
                                              int n, int F, int dorelu) {
  int b = blockIdx.y, i0 = blockIdx.x * 4, t = threadIdx.x;
  __shared__ float sA[4 * 256];
  const float* Ab = A + (size_t)b * n * n;
  const float* dv = dinv + (size_t)b * n;
  for (int idx = t; idx < 4 * n; idx += 256) {
    int il = idx / n, j = idx - il * n;
    sA[il * n + j] = Ab[(size_t)(i0 + il) * n + j] * dv[j];
  }
  __syncthreads();
  const float* xwb = xw + (size_t)b * n * F;
  for (int idx = t; idx < 4 * F; idx += 256) {
    int il = idx / F, f = idx - il * F;
    int i = i0 + il;
    const float* sr = &sA[il * n];
    float acc = 0.f;
    for (int j = 0; j < n; j++) acc += sr[j] * xwb[(size_t)j * F + f];
    float di = dv[i];
    float v = di * acc + 2.f * di * di * xwb[(size_t)i * F + f] + bias[f];
    if (dorelu) v = fmaxf(v, 0.f);
    out[((size_t)b * n + i) * F + f] = v;
  }
}

// ---------- pooling scores: tanh(h.p / ||p||) ----------
__global__ __launch_bounds__(256) void k_score(const float* __restrict__ H,
                                               const float* __restrict__ p,
                                               float* __restrict__ sc, int total) {
  int idx = blockIdx.x * 256 + threadIdx.x;
  if (idx >= total) return;
  const float* hr = H + (size_t)idx * HID;
  float pn = 0.f, acc = 0.f;
  for (int k2 = 0; k2 < HID; k2++) {
    float pv = p[k2];
    pn += pv * pv;
    acc += hr[k2] * pv;
  }
  sc[idx] = tanhf(acc / sqrtf(pn));
}

// ---------- exact stable top-k via rank (desc, ties -> lower index) ----------
__global__ __launch_bounds__(256) void k_topk(const float* __restrict__ sc,
                                              int* __restrict__ perm,
                                              int n, int k) {
  int b = blockIdx.x, t = threadIdx.x;
  __shared__ float s[256];
  if (t < n) s[t] = sc[(size_t)b * n + t];
  __syncthreads();
  if (t < n) {
    float v = s[t];
    int r = 0;
    for (int j = 0; j < n; j++) {
      float u = s[j];
      r += (u > v) || (u == v && j < t);
    }
    if (r < k) perm[(size_t)b * k + r] = t;
  }
}

// ---------- pooled h: Hout[b,r,f] = H[b,perm[r],f] * sc[b,perm[r]] ----------
__global__ __launch_bounds__(256) void k_gather(const float* __restrict__ H,
                                                const float* __restrict__ sc,
                                                const int* __restrict__ perm,
                                                float* __restrict__ Hout,
                                                int n, int k, int total) {
  int idx = blockIdx.x * 256 + threadIdx.x;
  if (idx >= total) return;
  int f = idx % HID;
  int r = (idx / HID) % k;
  int b = idx / (HID * k);
  int pi = perm[(size_t)b * k + r];
  Hout[idx] = H[((size_t)b * n + pi) * HID + f] * sc[(size_t)b * n + pi];
}

// ---------- gathered augment: Ap[r,c] = (r==c)?0 : sum_j A[pr,j]A[pc,j] + 2A[pr,pc] ----------
__global__ __launch_bounds__(256) void k_aug(const float* __restrict__ A,
                                             const int* __restrict__ perm,
                                             float* __restrict__ Ap,
                                             int n, int k) {
  int b = blockIdx.y, r0 = blockIdx.x * 4, t = threadIdx.x;
  __shared__ float sR[4 * 256];
  __shared__ int spm[4];
  const float* Ab = A + (size_t)b * n * n;
  if (t < 4) spm[t] = perm[(size_t)b * k + r0 + t];
  __syncthreads();
  for (int idx = t; idx < 4 * n; idx += 256) {
    int rl = idx / n, j = idx - rl * n;
    sR[rl * n + j] = Ab[(size_t)spm[rl] * n + j];
  }
  __syncthreads();
  for (int c = t; c < k; c += 256) {
    int pc = perm[(size_t)b * k + c];
    const float* rowc = Ab + (size_t)pc * n;
    float a0 = 0.f, a1 = 0.f, a2 = 0.f, a3 = 0.f;
    for (int j = 0; j < n; j++) {
      float v = rowc[j];
      a0 += sR[j] * v;
      a1 += sR[n + j] * v;
      a2 += sR[2 * n + j] * v;
      a3 += sR[3 * n + j] * v;
    }
    float accs[4] = {a0, a1, a2, a3};
    for (int rl = 0; rl < 4; rl++) {
      int r = r0 + rl;
      float res = accs[rl] + 2.f * Ab[(size_t)spm[rl] * n + pc];
      Ap[((size_t)b * k + r) * k + c] = (r == c) ? 0.f : res;
    }
  }
}

// ---------- decoder scatter-add: Hdst[b,perm[r],f] += Hsrc[b,r,f] ----------
__global__ __launch_bounds__(256) void k_scatter(const int* __restrict__ perm,
                                                 const float* __restrict__ Hsrc,
                                                 float* __restrict__ Hdst,
                                                 int n, int k, int total) {
  int idx = blockIdx.x * 256 + threadIdx.x;
  if (idx >= total) return;
  int f = idx % HID;
  int r = (idx / HID) % k;
  int b = idx / (HID * k);
  int pi = perm[(size_t)b * k + r];
  Hdst[((size_t)b * n + pi) * HID + f] += Hsrc[idx];
}

// ---------- fused head: top-30 select -> c1 einsum+relu -> pairmax -> conv1d+relu -> dense+relu ----------
__global__ __launch_bounds__(256) void k_head(const float* __restrict__ HT,
                                              const float* __restrict__ c1W,
                                              const float* __restrict__ c1b,
                                              const float* __restrict__ c2W,
                                              const float* __restrict__ c2b,
                                              const float* __restrict__ oW,
                                              const float* __restrict__ ob,
                                              float* __restrict__ out) {
  int b = blockIdx.x, t = threadIdx.x;
  __shared__ float sc[256];
  __shared__ int ord[30];
  __shared__ float sp[30 * 97];
  __shared__ float y1[16 * 30];
  __shared__ float yp[16 * 15];
  __shared__ float yc[32 * 11];
  const float* Hb = HT + (size_t)b * NNODE * DOUT;
  sc[t] = Hb[(size_t)t * DOUT + (DOUT - 1)];
  __syncthreads();
  {
    float v = sc[t];
    int r = 0;
    for (int j = 0; j < 256; j++) {
      float u = sc[j];
      r += (u > v) || (u == v && j < t);
    }
    if (r < 30) ord[r] = t;
  }
  __syncthreads();
  for (int idx = t; idx < 30 * 97; idx += 256) {
    int r = idx / 97, d = idx - r * 97;
    sp[idx] = Hb[(size_t)ord[r] * DOUT + d];
  }
  __syncthreads();
  for (int idx = t; idx < 16 * 30; idx += 256) {
    int c = idx / 30, kk = idx - c * 30;
    float a = c1b[c];
    for (int d = 0; d < 97; d++) a += sp[kk * 97 + d] * c1W[c * 97 + d];
    y1[c * 30 + kk] = fmaxf(a, 0.f);
  }
  __syncthreads();
  for (int idx = t; idx < 16 * 15; idx += 256) {
    int c = idx / 15, t2 = idx - c * 15;
    yp[idx] = fmaxf(y1[c * 30 + 2 * t2], y1[c * 30 + 2 * t2 + 1]);
  }
  __syncthreads();
  for (int idx = t; idx < 32 * 11; idx += 256) {
    int o = idx / 11, t3 = idx - o * 11;
    float a = c2b[o];
    for (int i2 = 0; i2 < 16; i2++)
      for (int w = 0; w < 5; w++)
        a += yp[i2 * 15 + t3 + w] * c2W[(o * 16 + i2) * 5 + w];
    yc[o * 11 + t3] = fmaxf(a, 0.f);
  }
  __syncthreads();
  if (t < 32) {
    float a = ob[t];
    for (int q = 0; q < 352; q++) a += yc[q] * oW[q * 32 + t];
    out[(size_t)b * 32 + t] = fmaxf(a, 0.f);
  }
}

extern "C" void kernel_launch(void* const* d_in, const int* in_sizes, int n_in,
                              void* d_out, int out_size, void* d_ws, size_t ws_size,
                              hipStream_t stream) {
  const float* x   = (const float*)d_in[0];
  const float* A0  = (const float*)d_in[1];
  const float* dW0 = (const float*)d_in[2];
  const float* db0 = (const float*)d_in[3];
  const float* dW  = (const float*)d_in[4];
  const float* dbv = (const float*)d_in[5];
  const float* pp  = (const float*)d_in[6];
  const float* uW  = (const float*)d_in[7];
  const float* ub  = (const float*)d_in[8];
  const float* uWl = (const float*)d_in[9];
  const float* ubl = (const float*)d_in[10];
  const float* c1W = (const float*)d_in[11];
  const float* c1b = (const float*)d_in[12];
  const float* c2W = (const float*)d_in[13];
  const float* c2b = (const float*)d_in[14];
  const float* oW  = (const float*)d_in[15];
  const float* ob  = (const float*)d_in[16];
  float* out = (float*)d_out;

  float* base = (float*)d_ws;
  size_t off = 0;
  auto alloc = [&](size_t nel) { float* p = base + off; off += nel; return p; };
  float* H0 = alloc((size_t)BATCH * 256 * HID);
  float* H1 = alloc((size_t)BATCH * 128 * HID);
  float* H2 = alloc((size_t)BATCH * 64 * HID);
  float* H3 = alloc((size_t)BATCH * 32 * HID);
  float* H4 = alloc((size_t)BATCH * 16 * HID);
  float* HT = alloc((size_t)BATCH * 256 * DOUT);
  float* XW = alloc((size_t)BATCH * 256 * DOUT);
  float* A1 = alloc((size_t)BATCH * 128 * 128);
  float* A2 = alloc((size_t)BATCH * 64 * 64);
  float* A3 = alloc((size_t)BATCH * 32 * 32);
  float* A4 = alloc((size_t)BATCH * 16 * 16);
  float* D0 = alloc((size_t)BATCH * 256);
  float* D1 = alloc((size_t)BATCH * 128);
  float* D2 = alloc((size_t)BATCH * 64);
  float* D3 = alloc((size_t)BATCH * 32);
  float* D4 = alloc((size_t)BATCH * 16);
  float* SC = alloc((size_t)BATCH * 256);
  int* P1 = (int*)alloc((size_t)BATCH * 128);
  int* P2 = (int*)alloc((size_t)BATCH * 64);
  int* P3 = (int*)alloc((size_t)BATCH * 32);
  int* P4 = (int*)alloc((size_t)BATCH * 16);

  int ns[5] = {256, 128, 64, 32, 16};
  float* Hl[5] = {H0, H1, H2, H3, H4};
  float* Al[5] = {(float*)A0, A1, A2, A3, A4};
  float* Dl[5] = {D0, D1, D2, D3, D4};
  int* Pl[4] = {P1, P2, P3, P4};

  // ---- encoder: first GCN on input graph ----
  k_dinv<<<BATCH * 256 / 4, 256, 0, stream>>>(A0, D0, 256, BATCH * 256);
  k_xw<<<BATCH * 256 / 8, 256, 0, stream>>>(x, dW0, XW, BATCH * 256, FIN, HID);
  k_anxw<<<dim3(64, BATCH), 256, 0, stream>>>(A0, D0, XW, db0, H0, 256, HID, 1);

  // ---- encoder levels ----
  for (int i = 0; i < 4; i++) {
    int n = ns[i], kk = ns[i + 1];
    k_score<<<(BATCH * n + 255) / 256, 256, 0, stream>>>(Hl[i], pp + i * HID, SC, BATCH * n);
    k_topk<<<BATCH, 256, 0, stream>>>(SC, Pl[i], n, kk);
    k_gather<<<(BATCH * kk * HID + 255) / 256, 256, 0, stream>>>(Hl[i], SC, Pl[i], Hl[i + 1], n, kk, BATCH * kk * HID);
    k_aug<<<dim3(kk / 4, BATCH), 256, 0, stream>>>(Al[i], Pl[i], Al[i + 1], n, kk);
    k_dinv<<<BATCH * kk / 4, 256, 0, stream>>>(Al[i + 1], Dl[i + 1], kk, BATCH * kk);
    k_xw<<<BATCH * kk / 8, 256, 0, stream>>>(Hl[i + 1], dW + (size_t)i * HID * HID, XW, BATCH * kk, HID, HID);
    k_anxw<<<dim3(kk / 4, BATCH), 256, 0, stream>>>(Al[i + 1], Dl[i + 1], XW, dbv + i * HID, Hl[i + 1], kk, HID, 1);
  }

  // ---- decoder ----
  for (int i = 0; i < 4; i++) {
    int j = 3 - i, nj = ns[j], kj = ns[j + 1];
    k_scatter<<<(BATCH * kj * HID + 255) / 256, 256, 0, stream>>>(Pl[j], Hl[j + 1], Hl[j], nj, kj, BATCH * kj * HID);
    if (i < 3) {
      k_xw<<<BATCH * nj / 8, 256, 0, stream>>>(Hl[j], uW + (size_t)i * HID * HID, XW, BATCH * nj, HID, HID);
      k_anxw<<<dim3(nj / 4, BATCH), 256, 0, stream>>>(Al[j], Dl[j], XW, ub + i * HID, Hl[j], nj, HID, 1);
    } else {
      k_xw<<<BATCH * 256 / 8, 256, 0, stream>>>(H0, uWl, XW, BATCH * 256, HID, DOUT);
      k_anxw<<<dim3(64, BATCH), 256, 0, stream>>>(A0, D0, XW, ubl, HT, 256, DOUT, 0);
    }
  }

  // ---- fused head ----
  k_head<<<BATCH, 256, 0, stream>>>(HT, c1W, c1b, c2W, c2b, oW, ob, out);
}

// Round 2
// 939.577 us; speedup vs baseline: 1.3662x; 1.3662x over previous
//
#include <hip/hip_runtime.h>
#include <math.h>

#define BATCH 256
#define NNODE 256
#define FIN   128
#define HID   48
#define DOUT  97

typedef __attribute__((ext_vector_type(8))) short bf16x8_t;
typedef __attribute__((ext_vector_type(4))) float f32x4_t;

__device__ inline unsigned short f2bf(float x) {
  unsigned u = __float_as_uint(x);
  u += 0x7fff + ((u >> 16) & 1);
  return (unsigned short)(u >> 16);
}
__device__ inline float bf2f(unsigned short h) {
  return __uint_as_float(((unsigned)h) << 16);
}

// ---------- rowsum -> dinv = 1/sqrt(rowsum(A)+2) ----------
__global__ __launch_bounds__(256) void k_dinv(const float* __restrict__ A,
                                              float* __restrict__ dinv,
                                              int n, int rows) {
  int wid  = (blockIdx.x * blockDim.x + threadIdx.x) >> 6;
  int lane = threadIdx.x & 63;
  if (wid >= rows) return;
  const float* row = A + (size_t)wid * n;
  float s = 0.f;
  for (int j = lane; j < n; j += 64) s += row[j];
  #pragma unroll
  for (int o = 32; o > 0; o >>= 1) s += __shfl_down(s, o);
  if (lane == 0) dinv[wid] = 1.0f / sqrtf(s + 2.0f);
}

// ---------- XW = H @ W  (rows x K) @ (K x F) ----------
__global__ __launch_bounds__(256) void k_xw(const float* __restrict__ H,
                                            const float* __restrict__ W,
                                            float* __restrict__ XW,
                                            int rowsTotal, int K, int F) {
  __shared__ float sW[6144];
  __shared__ float sH[1024];
  int t = threadIdx.x;
  for (int i = t; i < K * F; i += 256) sW[i] = W[i];
  long row0 = (long)blockIdx.x * 8;
  int nrows = min(8, rowsTotal - (int)row0);
  for (int i = t; i < nrows * K; i += 256) sH[i] = H[row0 * K + i];
  __syncthreads();
  for (int idx = t; idx < nrows * F; idx += 256) {
    int r = idx / F, f = idx - r * F;
    const float* hr = &sH[r * K];
    float acc = 0.f;
    for (int k2 = 0; k2 < K; k2++) acc += hr[k2] * sW[k2 * F + f];
    XW[(row0 + r) * F + f] = acc;
  }
}

// ---------- VALU fallback for small n ----------
__global__ __launch_bounds__(256) void k_anxw(const float* __restrict__ A,
                                              const float* __restrict__ dinv,
                                              const float* __restrict__ xw,
                                              const float* __restrict__ bias,
                                              float* __restrict__ out,
                                              int n, int F, int dorelu) {
  int b = blockIdx.y, i0 = blockIdx.x * 4, t = threadIdx.x;
  __shared__ float sA[4 * 256];
  const float* Ab = A + (size_t)b * n * n;
  const float* dv = dinv + (size_t)b * n;
  for (int idx = t; idx < 4 * n; idx += 256) {
    int il = idx / n, j = idx - il * n;
    sA[il * n + j] = Ab[(size_t)(i0 + il) * n + j] * dv[j];
  }
  __syncthreads();
  const float* xwb = xw + (size_t)b * n * F;
  for (int idx = t; idx < 4 * F; idx += 256) {
    int il = idx / F, f = idx - il * F;
    int i = i0 + il;
    const float* sr = &sA[il * n];
    float acc = 0.f;
    for (int j = 0; j < n; j++) acc += sr[j] * xwb[(size_t)j * F + f];
    float di = dv[i];
    float v = di * acc + 2.f * di * di * xwb[(size_t)i * F + f] + bias[f];
    if (dorelu) v = fmaxf(v, 0.f);
    out[((size_t)b * n + i) * F + f] = v;
  }
}

// ---------- A (fp32, exact small ints) -> bf16 ----------
__global__ __launch_bounds__(256) void k_convA(const float* __restrict__ A,
                                               unsigned short* __restrict__ Abf,
                                               size_t total) {
  size_t idx = (size_t)blockIdx.x * 256 + threadIdx.x;
  if (idx < total) Abf[idx] = f2bf(A[idx]);
}

// ---------- Yt_hi/lo[b][f][j] = split_bf16( dinv[j] * xw[j][f] ), transposed ----------
__global__ __launch_bounds__(256) void k_convY(const float* __restrict__ xw,
                                               const float* __restrict__ dinv,
                                               unsigned short* __restrict__ Yh,
                                               unsigned short* __restrict__ Yl,
                                               int n, int F, int Fpad) {
  __shared__ float tile[64][113];
  int b = blockIdx.y, j0 = blockIdx.x * 64, t = threadIdx.x;
  for (int idx = t; idx < 64 * Fpad; idx += 256) {
    int jl = idx / Fpad, f = idx - jl * Fpad;
    int j = j0 + jl;
    float v = (f < F) ? dinv[(size_t)b * n + j] * xw[((size_t)b * n + j) * F + f] : 0.f;
    tile[jl][f] = v;
  }
  __syncthreads();
  for (int idx = t; idx < Fpad * 64; idx += 256) {
    int f = idx / 64, jl = idx - f * 64;
    float v = tile[jl][f];
    unsigned short hi = f2bf(v);
    unsigned short lo = f2bf(v - bf2f(hi));
    size_t o = ((size_t)b * Fpad + f) * n + j0 + jl;
    Yh[o] = hi;
    Yl[o] = lo;
  }
}

// ---------- MFMA: out = relu?( d_i * (A @ (Yhi+Ylo)) + 2 d_i^2 xw_i + bias ) ----------
// one 16x16 output tile per wave, K-step 32, split-bf16 B operand
__global__ __launch_bounds__(256) void k_anxw_mfma(
    const unsigned short* __restrict__ Abf,  // B x n x n (bf16, exact)
    const float* __restrict__ dinv,          // B x n
    const unsigned short* __restrict__ Yh,   // B x Fpad x n
    const unsigned short* __restrict__ Yl,   // B x Fpad x n
    const float* __restrict__ xw,            // B x n x F
    const float* __restrict__ bias,          // F
    float* __restrict__ out,                 // B x n x F
    int n, int F, int Fpad, int nTiles, int dorelu) {
  int wid = (blockIdx.x * 256 + threadIdx.x) >> 6;
  if (wid >= nTiles) return;
  int lane = threadIdx.x & 63;
  int nIT = n >> 4, nFT = Fpad >> 4;
  int b = wid / (nIT * nFT);
  int rem = wid - b * (nIT * nFT);
  int it = rem / nFT, ft = rem - it * nFT;
  int r = lane & 15, q = lane >> 4;
  const unsigned short* Ap  = Abf + ((size_t)b * n + it * 16 + r) * n + q * 8;
  const unsigned short* Yhp = Yh + ((size_t)b * Fpad + ft * 16 + r) * n + q * 8;
  const unsigned short* Ylp = Yl + ((size_t)b * Fpad + ft * 16 + r) * n + q * 8;
  f32x4_t acc = {0.f, 0.f, 0.f, 0.f};
  for (int k0 = 0; k0 < n; k0 += 32) {
    bf16x8_t a  = *(const bf16x8_t*)(Ap + k0);
    bf16x8_t bh = *(const bf16x8_t*)(Yhp + k0);
    bf16x8_t bl = *(const bf16x8_t*)(Ylp + k0);
    acc = __builtin_amdgcn_mfma_f32_16x16x32_bf16(a, bh, acc, 0, 0, 0);
    acc = __builtin_amdgcn_mfma_f32_16x16x32_bf16(a, bl, acc, 0, 0, 0);
  }
  int f = ft * 16 + r;
  if (f < F) {
    #pragma unroll
    for (int reg = 0; reg < 4; reg++) {
      int i = it * 16 + q * 4 + reg;
      float di = dinv[(size_t)b * n + i];
      float xv = xw[((size_t)b * n + i) * F + f];
      float v = di * acc[reg] + 2.f * di * di * xv + bias[f];
      if (dorelu) v = fmaxf(v, 0.f);
      out[((size_t)b * n + i) * F + f] = v;
    }
  }
}

// ---------- pooling scores: tanh(h.p / ||p||) ----------
__global__ __launch_bounds__(256) void k_score(const float* __restrict__ H,
                                               const float* __restrict__ p,
                                               float* __restrict__ sc, int total) {
  int idx = blockIdx.x * 256 + threadIdx.x;
  if (idx >= total) return;
  const float* hr = H + (size_t)idx * HID;
  float pn = 0.f, acc = 0.f;
  for (int k2 = 0; k2 < HID; k2++) {
    float pv = p[k2];
    pn += pv * pv;
    acc += hr[k2] * pv;
  }
  sc[idx] = tanhf(acc / sqrtf(pn));
}

// ---------- exact stable top-k via rank ----------
__global__ __launch_bounds__(256) void k_topk(const float* __restrict__ sc,
                                              int* __restrict__ perm,
                                              int n, int k) {
  int b = blockIdx.x, t = threadIdx.x;
  __shared__ float s[256];
  if (t < n) s[t] = sc[(size_t)b * n + t];
  __syncthreads();
  if (t < n) {
    float v = s[t];
    int r = 0;
    for (int j = 0; j < n; j++) {
      float u = s[j];
      r += (u > v) || (u == v && j < t);
    }
    if (r < k) perm[(size_t)b * k + r] = t;
  }
}

// ---------- pooled h gather ----------
__global__ __launch_bounds__(256) void k_gather(const float* __restrict__ H,
                                                const float* __restrict__ sc,
                                                const int* __restrict__ perm,
                                                float* __restrict__ Hout,
                                                int n, int k, int total) {
  int idx = blockIdx.x * 256 + threadIdx.x;
  if (idx >= total) return;
  int f = idx % HID;
  int r = (idx / HID) % k;
  int b = idx / (HID * k);
  int pi = perm[(size_t)b * k + r];
  Hout[idx] = H[((size_t)b * n + pi) * HID + f] * sc[(size_t)b * n + pi];
}

// ---------- gathered augment ----------
__global__ __launch_bounds__(256) void k_aug(const float* __restrict__ A,
                                             const int* __restrict__ perm,
                                             float* __restrict__ Ap,
                                             int n, int k) {
  int b = blockIdx.y, r0 = blockIdx.x * 4, t = threadIdx.x;
  __shared__ float sR[4 * 256];
  __shared__ int spm[4];
  const float* Ab = A + (size_t)b * n * n;
  if (t < 4) spm[t] = perm[(size_t)b * k + r0 + t];
  __syncthreads();
  for (int idx = t; idx < 4 * n; idx += 256) {
    int rl = idx / n, j = idx - rl * n;
    sR[rl * n + j] = Ab[(size_t)spm[rl] * n + j];
  }
  __syncthreads();
  for (int c = t; c < k; c += 256) {
    int pc = perm[(size_t)b * k + c];
    const float* rowc = Ab + (size_t)pc * n;
    float a0 = 0.f, a1 = 0.f, a2 = 0.f, a3 = 0.f;
    for (int j = 0; j < n; j++) {
      float v = rowc[j];
      a0 += sR[j] * v;
      a1 += sR[n + j] * v;
      a2 += sR[2 * n + j] * v;
      a3 += sR[3 * n + j] * v;
    }
    float accs[4] = {a0, a1, a2, a3};
    for (int rl = 0; rl < 4; rl++) {
      int r = r0 + rl;
      float res = accs[rl] + 2.f * Ab[(size_t)spm[rl] * n + pc];
      Ap[((size_t)b * k + r) * k + c] = (r == c) ? 0.f : res;
    }
  }
}

// ---------- decoder scatter-add ----------
__global__ __launch_bounds__(256) void k_scatter(const int* __restrict__ perm,
                                                 const float* __restrict__ Hsrc,
                                                 float* __restrict__ Hdst,
                                                 int n, int k, int total) {
  int idx = blockIdx.x * 256 + threadIdx.x;
  if (idx >= total) return;
  int f = idx % HID;
  int r = (idx / HID) % k;
  int b = idx / (HID * k);
  int pi = perm[(size_t)b * k + r];
  Hdst[((size_t)b * n + pi) * HID + f] += Hsrc[idx];
}

// ---------- fused head ----------
__global__ __launch_bounds__(256) void k_head(const float* __restrict__ HT,
                                              const float* __restrict__ c1W,
                                              const float* __restrict__ c1b,
                                              const float* __restrict__ c2W,
                                              const float* __restrict__ c2b,
                                              const float* __restrict__ oW,
                                              const float* __restrict__ ob,
                                              float* __restrict__ out) {
  int b = blockIdx.x, t = threadIdx.x;
  __shared__ float sc[256];
  __shared__ int ord[30];
  __shared__ float sp[30 * 97];
  __shared__ float y1[16 * 30];
  __shared__ float yp[16 * 15];
  __shared__ float yc[32 * 11];
  const float* Hb = HT + (size_t)b * NNODE * DOUT;
  sc[t] = Hb[(size_t)t * DOUT + (DOUT - 1)];
  __syncthreads();
  {
    float v = sc[t];
    int r = 0;
    for (int j = 0; j < 256; j++) {
      float u = sc[j];
      r += (u > v) || (u == v && j < t);
    }
    if (r < 30) ord[r] = t;
  }
  __syncthreads();
  for (int idx = t; idx < 30 * 97; idx += 256) {
    int r = idx / 97, d = idx - r * 97;
    sp[idx] = Hb[(size_t)ord[r] * DOUT + d];
  }
  __syncthreads();
  for (int idx = t; idx < 16 * 30; idx += 256) {
    int c = idx / 30, kk = idx - c * 30;
    float a = c1b[c];
    for (int d = 0; d < 97; d++) a += sp[kk * 97 + d] * c1W[c * 97 + d];
    y1[c * 30 + kk] = fmaxf(a, 0.f);
  }
  __syncthreads();
  for (int idx = t; idx < 16 * 15; idx += 256) {
    int c = idx / 15, t2 = idx - c * 15;
    yp[idx] = fmaxf(y1[c * 30 + 2 * t2], y1[c * 30 + 2 * t2 + 1]);
  }
  __syncthreads();
  for (int idx = t; idx < 32 * 11; idx += 256) {
    int o = idx / 11, t3 = idx - o * 11;
    float a = c2b[o];
    for (int i2 = 0; i2 < 16; i2++)
      for (int w = 0; w < 5; w++)
        a += yp[i2 * 15 + t3 + w] * c2W[(o * 16 + i2) * 5 + w];
    yc[o * 11 + t3] = fmaxf(a, 0.f);
  }
  __syncthreads();
  if (t < 32) {
    float a = ob[t];
    for (int q = 0; q < 352; q++) a += yc[q] * oW[q * 32 + t];
    out[(size_t)b * 32 + t] = fmaxf(a, 0.f);
  }
}

extern "C" void kernel_launch(void* const* d_in, const int* in_sizes, int n_in,
                              void* d_out, int out_size, void* d_ws, size_t ws_size,
                              hipStream_t stream) {
  const float* x   = (const float*)d_in[0];
  const float* A0  = (const float*)d_in[1];
  const float* dW0 = (const float*)d_in[2];
  const float* db0 = (const float*)d_in[3];
  const float* dW  = (const float*)d_in[4];
  const float* dbv = (const float*)d_in[5];
  const float* pp  = (const float*)d_in[6];
  const float* uW  = (const float*)d_in[7];
  const float* ub  = (const float*)d_in[8];
  const float* uWl = (const float*)d_in[9];
  const float* ubl = (const float*)d_in[10];
  const float* c1W = (const float*)d_in[11];
  const float* c1b = (const float*)d_in[12];
  const float* c2W = (const float*)d_in[13];
  const float* c2b = (const float*)d_in[14];
  const float* oW  = (const float*)d_in[15];
  const float* ob  = (const float*)d_in[16];
  float* out = (float*)d_out;

  float* base = (float*)d_ws;
  size_t off = 0;
  auto alloc = [&](size_t nel) { nel = (nel + 3) & ~(size_t)3; float* p = base + off; off += nel; return p; };
  float* H0 = alloc((size_t)BATCH * 256 * HID);
  float* H1 = alloc((size_t)BATCH * 128 * HID);
  float* H2 = alloc((size_t)BATCH * 64 * HID);
  float* H3 = alloc((size_t)BATCH * 32 * HID);
  float* H4 = alloc((size_t)BATCH * 16 * HID);
  float* HT = alloc((size_t)BATCH * 256 * DOUT);
  float* XW = alloc((size_t)BATCH * 256 * DOUT);
  float* A1 = alloc((size_t)BATCH * 128 * 128);
  float* A2 = alloc((size_t)BATCH * 64 * 64);
  float* A3 = alloc((size_t)BATCH * 32 * 32);
  float* A4 = alloc((size_t)BATCH * 16 * 16);
  float* D0 = alloc((size_t)BATCH * 256);
  float* D1 = alloc((size_t)BATCH * 128);
  float* D2 = alloc((size_t)BATCH * 64);
  float* D3 = alloc((size_t)BATCH * 32);
  float* D4 = alloc((size_t)BATCH * 16);
  float* SC = alloc((size_t)BATCH * 256);
  int* P1 = (int*)alloc((size_t)BATCH * 128);
  int* P2 = (int*)alloc((size_t)BATCH * 64);
  int* P3 = (int*)alloc((size_t)BATCH * 32);
  int* P4 = (int*)alloc((size_t)BATCH * 16);
  // bf16 buffers (2 bytes/elem, carved from float workspace)
  unsigned short* Abf0 = (unsigned short*)alloc((size_t)BATCH * 256 * 256 / 2);
  unsigned short* Abf1 = (unsigned short*)alloc((size_t)BATCH * 128 * 128 / 2);
  unsigned short* Yth  = (unsigned short*)alloc((size_t)BATCH * 112 * 256 / 2);
  unsigned short* Ytl  = (unsigned short*)alloc((size_t)BATCH * 112 * 256 / 2);

  int ns[5] = {256, 128, 64, 32, 16};
  float* Hl[5] = {H0, H1, H2, H3, H4};
  float* Al[5] = {(float*)A0, A1, A2, A3, A4};
  float* Dl[5] = {D0, D1, D2, D3, D4};
  int* Pl[4] = {P1, P2, P3, P4};

  // ---- encoder: first GCN on input graph (MFMA path, n=256, F=48) ----
  k_dinv<<<BATCH * 256 / 4, 256, 0, stream>>>(A0, D0, 256, BATCH * 256);
  {
    size_t tot = (size_t)BATCH * 256 * 256;
    k_convA<<<(int)((tot + 255) / 256), 256, 0, stream>>>(A0, Abf0, tot);
  }
  k_xw<<<BATCH * 256 / 8, 256, 0, stream>>>(x, dW0, XW, BATCH * 256, FIN, HID);
  k_convY<<<dim3(4, BATCH), 256, 0, stream>>>(XW, D0, Yth, Ytl, 256, HID, 48);
  {
    int nT = BATCH * 16 * 3;
    k_anxw_mfma<<<(nT + 3) / 4, 256, 0, stream>>>(Abf0, D0, Yth, Ytl, XW, db0, H0,
                                                  256, HID, 48, nT, 1);
  }

  // ---- encoder levels ----
  for (int i = 0; i < 4; i++) {
    int n = ns[i], kk = ns[i + 1];
    k_score<<<(BATCH * n + 255) / 256, 256, 0, stream>>>(Hl[i], pp + i * HID, SC, BATCH * n);
    k_topk<<<BATCH, 256, 0, stream>>>(SC, Pl[i], n, kk);
    k_gather<<<(BATCH * kk * HID + 255) / 256, 256, 0, stream>>>(Hl[i], SC, Pl[i], Hl[i + 1], n, kk, BATCH * kk * HID);
    k_aug<<<dim3(kk / 4, BATCH), 256, 0, stream>>>(Al[i], Pl[i], Al[i + 1], n, kk);
    k_dinv<<<BATCH * kk / 4, 256, 0, stream>>>(Al[i + 1], Dl[i + 1], kk, BATCH * kk);
    k_xw<<<BATCH * kk / 8, 256, 0, stream>>>(Hl[i + 1], dW + (size_t)i * HID * HID, XW, BATCH * kk, HID, HID);
    if (kk == 128) {
      size_t tot = (size_t)BATCH * 128 * 128;
      k_convA<<<(int)((tot + 255) / 256), 256, 0, stream>>>(A1, Abf1, tot);
      k_convY<<<dim3(2, BATCH), 256, 0, stream>>>(XW, D1, Yth, Ytl, 128, HID, 48);
      int nT = BATCH * 8 * 3;
      k_anxw_mfma<<<(nT + 3) / 4, 256, 0, stream>>>(Abf1, D1, Yth, Ytl, XW, dbv + i * HID,
                                                    Hl[i + 1], 128, HID, 48, nT, 1);
    } else {
      k_anxw<<<dim3(kk / 4, BATCH), 256, 0, stream>>>(Al[i + 1], Dl[i + 1], XW, dbv + i * HID, Hl[i + 1], kk, HID, 1);
    }
  }

  // ---- decoder ----
  for (int i = 0; i < 4; i++) {
    int j = 3 - i, nj = ns[j], kj = ns[j + 1];
    k_scatter<<<(BATCH * kj * HID + 255) / 256, 256, 0, stream>>>(Pl[j], Hl[j + 1], Hl[j], nj, kj, BATCH * kj * HID);
    if (i < 3) {
      k_xw<<<BATCH * nj / 8, 256, 0, stream>>>(Hl[j], uW + (size_t)i * HID * HID, XW, BATCH * nj, HID, HID);
      if (nj == 128) {
        k_convY<<<dim3(2, BATCH), 256, 0, stream>>>(XW, D1, Yth, Ytl, 128, HID, 48);
        int nT = BATCH * 8 * 3;
        k_anxw_mfma<<<(nT + 3) / 4, 256, 0, stream>>>(Abf1, D1, Yth, Ytl, XW, ub + i * HID,
                                                      Hl[j], 128, HID, 48, nT, 1);
      } else {
        k_anxw<<<dim3(nj / 4, BATCH), 256, 0, stream>>>(Al[j], Dl[j], XW, ub + i * HID, Hl[j], nj, HID, 1);
      }
    } else {
      k_xw<<<BATCH * 256 / 8, 256, 0, stream>>>(H0, uWl, XW, BATCH * 256, HID, DOUT);
      k_convY<<<dim3(4, BATCH), 256, 0, stream>>>(XW, D0, Yth, Ytl, 256, DOUT, 112);
      int nT = BATCH * 16 * 7;
      k_anxw_mfma<<<(nT + 3) / 4, 256, 0, stream>>>(Abf0, D0, Yth, Ytl, XW, ubl, HT,
                                                    256, DOUT, 112, nT, 0);
    }
  }

  // ---- fused head ----
  k_head<<<BATCH, 256, 0, stream>>>(HT, c1W, c1b, c2W, c2b, oW, ob, out);
}

// Round 4
// 777.295 us; speedup vs baseline: 1.6514x; 1.2088x over previous
//
#include <hip/hip_runtime.h>
#include <math.h>

#define BATCH 256
#define NNODE 256
#define FIN   128
#define HID   48
#define DOUT  97

typedef __attribute__((ext_vector_type(8))) short bf16x8_t;
typedef __attribute__((ext_vector_type(4))) float f32x4_t;

__device__ inline unsigned short f2bf(float x) {
  unsigned u = __float_as_uint(x);
  u += 0x7fff + ((u >> 16) & 1);
  return (unsigned short)(u >> 16);
}
__device__ inline float bf2f(unsigned short h) {
  return __uint_as_float(((unsigned)h) << 16);
}

// ---------- rowsum -> dinv = 1/sqrt(rowsum(A)+2) ----------
__global__ __launch_bounds__(256) void k_dinv(const float* __restrict__ A,
                                              float* __restrict__ dinv,
                                              int n, int rows) {
  int wid  = (blockIdx.x * blockDim.x + threadIdx.x) >> 6;
  int lane = threadIdx.x & 63;
  if (wid >= rows) return;
  const float* row = A + (size_t)wid * n;
  float s = 0.f;
  for (int j = lane; j < n; j += 64) s += row[j];
  #pragma unroll
  for (int o = 32; o > 0; o >>= 1) s += __shfl_down(s, o);
  if (lane == 0) dinv[wid] = 1.0f / sqrtf(s + 2.0f);
}

// ---------- A (fp32, exact small ints) -> bf16 ----------
__global__ __launch_bounds__(256) void k_convA(const float* __restrict__ A,
                                               unsigned short* __restrict__ Abf,
                                               size_t total) {
  size_t idx = (size_t)blockIdx.x * 256 + threadIdx.x;
  if (idx < total) Abf[idx] = f2bf(A[idx]);
}

// ---------- XW = H @ W (fp32 VALU — keeps H bit-exact vs reference-order fp32) ----------
__global__ __launch_bounds__(256) void k_xw(const float* __restrict__ H,
                                            const float* __restrict__ W,
                                            float* __restrict__ XW,
                                            int rowsTotal, int K, int F) {
  __shared__ float sW[6144];
  __shared__ float sH[1024];
  int t = threadIdx.x;
  for (int i = t; i < K * F; i += 256) sW[i] = W[i];
  long row0 = (long)blockIdx.x * 8;
  int nrows = min(8, rowsTotal - (int)row0);
  for (int i = t; i < nrows * K; i += 256) sH[i] = H[row0 * K + i];
  __syncthreads();
  for (int idx = t; idx < nrows * F; idx += 256) {
    int r = idx / F, f = idx - r * F;
    const float* hr = &sH[r * K];
    float acc = 0.f;
    for (int k2 = 0; k2 < K; k2++) acc += hr[k2] * sW[k2 * F + f];
    XW[(row0 + r) * F + f] = acc;
  }
}

// ---------- MFMA augment (EXACT): Ap[r,c] = (r==c)?0 : sum_j A[pr,j]A[pc,j] + 2A[pr,pc] ----------
// A entries exact small ints in bf16; fp32 accumulation of ints is exact -> zero error.
__global__ __launch_bounds__(256) void k_aug_mfma(const unsigned short* __restrict__ Abf,
                                                  const int* __restrict__ perm,
                                                  float* __restrict__ Ap,
                                                  unsigned short* __restrict__ Apbf,
                                                  int n, int k, int nTiles) {
  int wid = (blockIdx.x * 256 + threadIdx.x) >> 6;
  if (wid >= nTiles) return;
  int lane = threadIdx.x & 63;
  int kt = k >> 4;
  int b = wid / (kt * kt);
  int rem = wid - b * (kt * kt);
  int it = rem / kt, ft = rem - it * kt;
  int r = lane & 15, q = lane >> 4;
  const int* pm = perm + (size_t)b * k;
  int rowA = pm[it * 16 + r];
  int rowB = pm[ft * 16 + r];
  const unsigned short* Ab = Abf + (size_t)b * n * n;
  const unsigned short* pa = Ab + (size_t)rowA * n + q * 8;
  const unsigned short* pb = Ab + (size_t)rowB * n + q * 8;
  f32x4_t acc = {0.f, 0.f, 0.f, 0.f};
  for (int k0 = 0; k0 < n; k0 += 32) {
    bf16x8_t a  = *(const bf16x8_t*)(pa + k0);
    bf16x8_t bv = *(const bf16x8_t*)(pb + k0);
    acc = __builtin_amdgcn_mfma_f32_16x16x32_bf16(a, bv, acc, 0, 0, 0);
  }
  int c = ft * 16 + r;                       // output column; rowB == perm[c]
  const unsigned short* rowBp = Ab + (size_t)rowB * n;
  #pragma unroll
  for (int reg = 0; reg < 4; reg++) {
    int rr = it * 16 + q * 4 + reg;
    int pr = pm[rr];
    float v = acc[reg] + 2.f * bf2f(rowBp[pr]);  // A[pc][pr] == A[pr][pc] (symmetry)
    if (rr == c) v = 0.f;
    Ap[((size_t)b * k + rr) * k + c] = v;
    if (Apbf) Apbf[((size_t)b * k + rr) * k + c] = f2bf(v);
  }
}

// ---------- VALU augment for tiny levels ----------
__global__ __launch_bounds__(256) void k_aug(const float* __restrict__ A,
                                             const int* __restrict__ perm,
                                             float* __restrict__ Ap,
                                             int n, int k) {
  int b = blockIdx.y, r0 = blockIdx.x * 4, t = threadIdx.x;
  __shared__ float sR[4 * 256];
  __shared__ int spm[4];
  const float* Ab = A + (size_t)b * n * n;
  if (t < 4) spm[t] = perm[(size_t)b * k + r0 + t];
  __syncthreads();
  for (int idx = t; idx < 4 * n; idx += 256) {
    int rl = idx / n, j = idx - rl * n;
    sR[rl * n + j] = Ab[(size_t)spm[rl] * n + j];
  }
  __syncthreads();
  for (int c = t; c < k; c += 256) {
    int pc = perm[(size_t)b * k + c];
    const float* rowc = Ab + (size_t)pc * n;
    float a0 = 0.f, a1 = 0.f, a2 = 0.f, a3 = 0.f;
    for (int j = 0; j < n; j++) {
      float v = rowc[j];
      a0 += sR[j] * v;
      a1 += sR[n + j] * v;
      a2 += sR[2 * n + j] * v;
      a3 += sR[3 * n + j] * v;
    }
    float accs[4] = {a0, a1, a2, a3};
    for (int rl = 0; rl < 4; rl++) {
      int r = r0 + rl;
      float res = accs[rl] + 2.f * Ab[(size_t)spm[rl] * n + pc];
      Ap[((size_t)b * k + r) * k + c] = (r == c) ? 0.f : res;
    }
  }
}

// ---------- VALU anxw for small n ----------
__global__ __launch_bounds__(256) void k_anxw(const float* __restrict__ A,
                                              const float* __restrict__ dinv,
                                              const float* __restrict__ xw,
                                              const float* __restrict__ bias,
                                              float* __restrict__ out,
                                              int n, int F, int dorelu) {
  int b = blockIdx.y, i0 = blockIdx.x * 4, t = threadIdx.x;
  __shared__ float sA[4 * 256];
  const float* Ab = A + (size_t)b * n * n;
  const float* dv = dinv + (size_t)b * n;
  for (int idx = t; idx < 4 * n; idx += 256) {
    int il = idx / n, j = idx - il * n;
    sA[il * n + j] = Ab[(size_t)(i0 + il) * n + j] * dv[j];
  }
  __syncthreads();
  const float* xwb = xw + (size_t)b * n * F;
  for (int idx = t; idx < 4 * F; idx += 256) {
    int il = idx / F, f = idx - il * F;
    int i = i0 + il;
    const float* sr = &sA[il * n];
    float acc = 0.f;
    for (int j = 0; j < n; j++) acc += sr[j] * xwb[(size_t)j * F + f];
    float di = dv[i];
    float v = di * acc + 2.f * di * di * xwb[(size_t)i * F + f] + bias[f];
    if (dorelu) v = fmaxf(v, 0.f);
    out[((size_t)b * n + i) * F + f] = v;
  }
}

// ---------- Yt_hi/lo[b][f][j] = split_bf16( dinv[j] * xw[j][f] ), transposed ----------
__global__ __launch_bounds__(256) void k_convY(const float* __restrict__ xw,
                                               const float* __restrict__ dinv,
                                               unsigned short* __restrict__ Yh,
                                               unsigned short* __restrict__ Yl,
                                               int n, int F, int Fpad) {
  __shared__ float tile[64][113];
  int b = blockIdx.y, j0 = blockIdx.x * 64, t = threadIdx.x;
  for (int idx = t; idx < 64 * Fpad; idx += 256) {
    int jl = idx / Fpad, f = idx - jl * Fpad;
    int j = j0 + jl;
    float v = (f < F) ? dinv[(size_t)b * n + j] * xw[((size_t)b * n + j) * F + f] : 0.f;
    tile[jl][f] = v;
  }
  __syncthreads();
  for (int idx = t; idx < Fpad * 64; idx += 256) {
    int f = idx / 64, jl = idx - f * 64;
    float v = tile[jl][f];
    unsigned short hi = f2bf(v);
    unsigned short lo = f2bf(v - bf2f(hi));
    size_t o = ((size_t)b * Fpad + f) * n + j0 + jl;
    Yh[o] = hi;
    Yl[o] = lo;
  }
}

// ---------- MFMA: out = relu?( d_i * (A @ (Yhi+Ylo)) + 2 d_i^2 xw_i + bias ) ----------
__global__ __launch_bounds__(256) void k_anxw_mfma(
    const unsigned short* __restrict__ Abf, const float* __restrict__ dinv,
    const unsigned short* __restrict__ Yh, const unsigned short* __restrict__ Yl,
    const float* __restrict__ xw, const float* __restrict__ bias,
    float* __restrict__ out, int n, int F, int Fpad, int nTiles, int dorelu) {
  int wid = (blockIdx.x * 256 + threadIdx.x) >> 6;
  if (wid >= nTiles) return;
  int lane = threadIdx.x & 63;
  int nIT = n >> 4, nFT = Fpad >> 4;
  int b = wid / (nIT * nFT);
  int rem = wid - b * (nIT * nFT);
  int it = rem / nFT, ft = rem - it * nFT;
  int r = lane & 15, q = lane >> 4;
  const unsigned short* Ap  = Abf + ((size_t)b * n + it * 16 + r) * n + q * 8;
  const unsigned short* Yhp = Yh + ((size_t)b * Fpad + ft * 16 + r) * n + q * 8;
  const unsigned short* Ylp = Yl + ((size_t)b * Fpad + ft * 16 + r) * n + q * 8;
  f32x4_t acc = {0.f, 0.f, 0.f, 0.f};
  for (int k0 = 0; k0 < n; k0 += 32) {
    bf16x8_t a  = *(const bf16x8_t*)(Ap + k0);
    bf16x8_t bh = *(const bf16x8_t*)(Yhp + k0);
    bf16x8_t bl = *(const bf16x8_t*)(Ylp + k0);
    acc = __builtin_amdgcn_mfma_f32_16x16x32_bf16(a, bh, acc, 0, 0, 0);
    acc = __builtin_amdgcn_mfma_f32_16x16x32_bf16(a, bl, acc, 0, 0, 0);
  }
  int f = ft * 16 + r;
  if (f < F) {
    #pragma unroll
    for (int reg = 0; reg < 4; reg++) {
      int i = it * 16 + q * 4 + reg;
      float di = dinv[(size_t)b * n + i];
      float xv = xw[((size_t)b * n + i) * F + f];
      float v = di * acc[reg] + 2.f * di * di * xv + bias[f];
      if (dorelu) v = fmaxf(v, 0.f);
      out[((size_t)b * n + i) * F + f] = v;
    }
  }
}

// ---------- fused pooling: score + exact top-k rank + gather ----------
__global__ __launch_bounds__(256) void k_pool(const float* __restrict__ H,
                                              const float* __restrict__ p,
                                              int* __restrict__ perm,
                                              float* __restrict__ Hout,
                                              int n, int k) {
  int b = blockIdx.x, t = threadIdx.x;
  __shared__ float s[256];
  __shared__ int sord[128];
  float pn = 0.f;
  #pragma unroll
  for (int j = 0; j < HID; j++) pn += p[j] * p[j];
  if (t < n) {
    const float* hr = H + ((size_t)b * n + t) * HID;
    float acc = 0.f;
    #pragma unroll
    for (int j = 0; j < HID; j++) acc += hr[j] * p[j];
    s[t] = tanhf(acc / sqrtf(pn));
  }
  __syncthreads();
  if (t < n) {
    float v = s[t];
    int r = 0;
    for (int j = 0; j < n; j++) {
      float u = s[j];
      r += (u > v) || (u == v && j < t);
    }
    if (r < k) { perm[(size_t)b * k + r] = t; sord[r] = t; }
  }
  __syncthreads();
  for (int idx = t; idx < k * HID; idx += 256) {
    int r = idx / HID, f = idx - r * HID;
    int pi = sord[r];
    Hout[((size_t)b * k + r) * HID + f] = H[((size_t)b * n + pi) * HID + f] * s[pi];
  }
}

// ---------- decoder scatter-add ----------
__global__ __launch_bounds__(256) void k_scatter(const int* __restrict__ perm,
                                                 const float* __restrict__ Hsrc,
                                                 float* __restrict__ Hdst,
                                                 int n, int k, int total) {
  int idx = blockIdx.x * 256 + threadIdx.x;
  if (idx >= total) return;
  int f = idx % HID;
  int r = (idx / HID) % k;
  int b = idx / (HID * k);
  int pi = perm[(size_t)b * k + r];
  Hdst[((size_t)b * n + pi) * HID + f] += Hsrc[idx];
}

// ---------- fused head ----------
__global__ __launch_bounds__(256) void k_head(const float* __restrict__ HT,
                                              const float* __restrict__ c1W,
                                              const float* __restrict__ c1b,
                                              const float* __restrict__ c2W,
                                              const float* __restrict__ c2b,
                                              const float* __restrict__ oW,
                                              const float* __restrict__ ob,
                                              float* __restrict__ out) {
  int b = blockIdx.x, t = threadIdx.x;
  __shared__ float sc[256];
  __shared__ int ord[30];
  __shared__ float sp[30 * 97];
  __shared__ float y1[16 * 30];
  __shared__ float yp[16 * 15];
  __shared__ float yc[32 * 11];
  const float* Hb = HT + (size_t)b * NNODE * DOUT;
  sc[t] = Hb[(size_t)t * DOUT + (DOUT - 1)];
  __syncthreads();
  {
    float v = sc[t];
    int r = 0;
    for (int j = 0; j < 256; j++) {
      float u = sc[j];
      r += (u > v) || (u == v && j < t);
    }
    if (r < 30) ord[r] = t;
  }
  __syncthreads();
  for (int idx = t; idx < 30 * 97; idx += 256) {
    int r = idx / 97, d = idx - r * 97;
    sp[idx] = Hb[(size_t)ord[r] * DOUT + d];
  }
  __syncthreads();
  for (int idx = t; idx < 16 * 30; idx += 256) {
    int c = idx / 30, kk = idx - c * 30;
    float a = c1b[c];
    for (int d = 0; d < 97; d++) a += sp[kk * 97 + d] * c1W[c * 97 + d];
    y1[c * 30 + kk] = fmaxf(a, 0.f);
  }
  __syncthreads();
  for (int idx = t; idx < 16 * 15; idx += 256) {
    int c = idx / 15, t2 = idx - c * 15;
    yp[idx] = fmaxf(y1[c * 30 + 2 * t2], y1[c * 30 + 2 * t2 + 1]);
  }
  __syncthreads();
  for (int idx = t; idx < 32 * 11; idx += 256) {
    int o = idx / 11, t3 = idx - o * 11;
    float a = c2b[o];
    for (int i2 = 0; i2 < 16; i2++)
      for (int w = 0; w < 5; w++)
        a += yp[i2 * 15 + t3 + w] * c2W[(o * 16 + i2) * 5 + w];
    yc[o * 11 + t3] = fmaxf(a, 0.f);
  }
  __syncthreads();
  if (t < 32) {
    float a = ob[t];
    for (int q = 0; q < 352; q++) a += yc[q] * oW[q * 32 + t];
    out[(size_t)b * 32 + t] = fmaxf(a, 0.f);
  }
}

extern "C" void kernel_launch(void* const* d_in, const int* in_sizes, int n_in,
                              void* d_out, int out_size, void* d_ws, size_t ws_size,
                              hipStream_t stream) {
  const float* x   = (const float*)d_in[0];
  const float* A0  = (const float*)d_in[1];
  const float* dW0 = (const float*)d_in[2];
  const float* db0 = (const float*)d_in[3];
  const float* dW  = (const float*)d_in[4];
  const float* dbv = (const float*)d_in[5];
  const float* pp  = (const float*)d_in[6];
  const float* uW  = (const float*)d_in[7];
  const float* ub  = (const float*)d_in[8];
  const float* uWl = (const float*)d_in[9];
  const float* ubl = (const float*)d_in[10];
  const float* c1W = (const float*)d_in[11];
  const float* c1b = (const float*)d_in[12];
  const float* c2W = (const float*)d_in[13];
  const float* c2b = (const float*)d_in[14];
  const float* oW  = (const float*)d_in[15];
  const float* ob  = (const float*)d_in[16];
  float* out = (float*)d_out;

  float* base = (float*)d_ws;
  size_t off = 0;
  auto alloc = [&](size_t nel) { nel = (nel + 3) & ~(size_t)3; float* p = base + off; off += nel; return p; };
  float* H0 = alloc((size_t)BATCH * 256 * HID);
  float* H1 = alloc((size_t)BATCH * 128 * HID);
  float* H2 = alloc((size_t)BATCH * 64 * HID);
  float* H3 = alloc((size_t)BATCH * 32 * HID);
  float* H4 = alloc((size_t)BATCH * 16 * HID);
  float* HT = alloc((size_t)BATCH * 256 * DOUT);
  float* XW = alloc((size_t)BATCH * 256 * DOUT);
  float* A1 = alloc((size_t)BATCH * 128 * 128);
  float* A2 = alloc((size_t)BATCH * 64 * 64);
  float* A3 = alloc((size_t)BATCH * 32 * 32);
  float* A4 = alloc((size_t)BATCH * 16 * 16);
  float* D0 = alloc((size_t)BATCH * 256);
  float* D1 = alloc((size_t)BATCH * 128);
  float* D2 = alloc((size_t)BATCH * 64);
  float* D3 = alloc((size_t)BATCH * 32);
  float* D4 = alloc((size_t)BATCH * 16);
  int* P1 = (int*)alloc((size_t)BATCH * 128);
  int* P2 = (int*)alloc((size_t)BATCH * 64);
  int* P3 = (int*)alloc((size_t)BATCH * 32);
  int* P4 = (int*)alloc((size_t)BATCH * 16);
  unsigned short* Abf0 = (unsigned short*)alloc((size_t)BATCH * 256 * 256 / 2);
  unsigned short* Abf1 = (unsigned short*)alloc((size_t)BATCH * 128 * 128 / 2);
  unsigned short* Yth  = (unsigned short*)alloc((size_t)BATCH * 112 * 256 / 2);
  unsigned short* Ytl  = (unsigned short*)alloc((size_t)BATCH * 112 * 256 / 2);

  int ns[5] = {256, 128, 64, 32, 16};
  float* Hl[5] = {H0, H1, H2, H3, H4};
  float* Al[5] = {(float*)A0, A1, A2, A3, A4};
  float* Dl[5] = {D0, D1, D2, D3, D4};
  int* Pl[4] = {P1, P2, P3, P4};

  // ---- prologue ----
  k_dinv<<<BATCH * 256 / 4, 256, 0, stream>>>(A0, D0, 256, BATCH * 256);
  {
    size_t tot = (size_t)BATCH * 256 * 256;
    k_convA<<<(int)((tot + 255) / 256), 256, 0, stream>>>(A0, Abf0, tot);
  }

  // ---- first GCN: XW = x @ dW0 (fp32 VALU), An@XW (MFMA, split-Y exact-A) ----
  k_xw<<<BATCH * 256 / 8, 256, 0, stream>>>(x, dW0, XW, BATCH * 256, FIN, HID);
  k_convY<<<dim3(4, BATCH), 256, 0, stream>>>(XW, D0, Yth, Ytl, 256, HID, 48);
  {
    int nT2 = BATCH * 16 * 3;
    k_anxw_mfma<<<(nT2 + 3) / 4, 256, 0, stream>>>(Abf0, D0, Yth, Ytl, XW, db0, H0,
                                                   256, HID, 48, nT2, 1);
  }

  // ---- encoder levels ----
  for (int i = 0; i < 4; i++) {
    int n = ns[i], kk = ns[i + 1];
    k_pool<<<BATCH, 256, 0, stream>>>(Hl[i], pp + i * HID, Pl[i], Hl[i + 1], n, kk);
    if (i <= 1) {
      int nT = BATCH * (kk / 16) * (kk / 16);
      k_aug_mfma<<<(nT + 3) / 4, 256, 0, stream>>>(i == 0 ? Abf0 : Abf1, Pl[i],
                                                   Al[i + 1],
                                                   i == 0 ? Abf1 : (unsigned short*)nullptr,
                                                   n, kk, nT);
    } else {
      k_aug<<<dim3(kk / 4, BATCH), 256, 0, stream>>>(Al[i], Pl[i], Al[i + 1], n, kk);
    }
    k_dinv<<<(BATCH * kk + 3) / 4, 256, 0, stream>>>(Al[i + 1], Dl[i + 1], kk, BATCH * kk);
    k_xw<<<(BATCH * kk + 7) / 8, 256, 0, stream>>>(Hl[i + 1], dW + (size_t)i * HID * HID,
                                                   XW, BATCH * kk, HID, HID);
    if (kk == 128) {
      k_convY<<<dim3(2, BATCH), 256, 0, stream>>>(XW, D1, Yth, Ytl, 128, HID, 48);
      int nT2 = BATCH * 8 * 3;
      k_anxw_mfma<<<(nT2 + 3) / 4, 256, 0, stream>>>(Abf1, D1, Yth, Ytl, XW, dbv + i * HID,
                                                     Hl[i + 1], 128, HID, 48, nT2, 1);
    } else {
      k_anxw<<<dim3(kk / 4, BATCH), 256, 0, stream>>>(Al[i + 1], Dl[i + 1], XW,
                                                      dbv + i * HID, Hl[i + 1], kk, HID, 1);
    }
  }

  // ---- decoder ----
  for (int i = 0; i < 4; i++) {
    int j = 3 - i, nj = ns[j], kj = ns[j + 1];
    k_scatter<<<(BATCH * kj * HID + 255) / 256, 256, 0, stream>>>(Pl[j], Hl[j + 1], Hl[j],
                                                                  nj, kj, BATCH * kj * HID);
    if (i < 3) {
      k_xw<<<(BATCH * nj + 7) / 8, 256, 0, stream>>>(Hl[j], uW + (size_t)i * HID * HID,
                                                     XW, BATCH * nj, HID, HID);
      if (nj == 128) {
        k_convY<<<dim3(2, BATCH), 256, 0, stream>>>(XW, D1, Yth, Ytl, 128, HID, 48);
        int nT2 = BATCH * 8 * 3;
        k_anxw_mfma<<<(nT2 + 3) / 4, 256, 0, stream>>>(Abf1, D1, Yth, Ytl, XW, ub + i * HID,
                                                       Hl[j], 128, HID, 48, nT2, 1);
      } else {
        k_anxw<<<dim3(nj / 4, BATCH), 256, 0, stream>>>(Al[j], Dl[j], XW, ub + i * HID,
                                                        Hl[j], nj, HID, 1);
      }
    } else {
      k_xw<<<BATCH * 256 / 8, 256, 0, stream>>>(H0, uWl, XW, BATCH * 256, HID, DOUT);
      k_convY<<<dim3(4, BATCH), 256, 0, stream>>>(XW, D0, Yth, Ytl, 256, DOUT, 112);
      int nT2 = BATCH * 16 * 7;
      k_anxw_mfma<<<(nT2 + 3) / 4, 256, 0, stream>>>(Abf0, D0, Yth, Ytl, XW, ubl, HT,
                                                     256, DOUT, 112, nT2, 0);
    }
  }

  // ---- fused head ----
  k_head<<<BATCH, 256, 0, stream>>>(HT, c1W, c1b, c2W, c2b, oW, ob, out);
}

// Round 5
// 670.994 us; speedup vs baseline: 1.9130x; 1.1584x over previous
//
#include <hip/hip_runtime.h>
#include <math.h>

#define BATCH 256
#define NNODE 256
#define FIN   128
#define HID   48
#define DOUT  97

typedef __attribute__((ext_vector_type(8))) short bf16x8_t;
typedef __attribute__((ext_vector_type(4))) float f32x4_t;

__device__ inline unsigned short f2bf(float x) {
  unsigned u = __float_as_uint(x);
  u += 0x7fff + ((u >> 16) & 1);
  return (unsigned short)(u >> 16);
}
__device__ inline float bf2f(unsigned short h) {
  return __uint_as_float(((unsigned)h) << 16);
}

// ---------- fused A0 pass: bf16 convert + rowsum -> dinv (exact: 0/1 entries) ----------
__global__ __launch_bounds__(256) void k_prepA(const float* __restrict__ A,
                                               unsigned short* __restrict__ Abf,
                                               float* __restrict__ dinv, int rows) {
  int wid = (blockIdx.x * 256 + threadIdx.x) >> 6;
  int lane = threadIdx.x & 63;
  if (wid >= rows) return;
  const float4* rp = (const float4*)(A + (size_t)wid * 256);
  float4 v = rp[lane];
  unsigned long long pk = (unsigned long long)f2bf(v.x)
                        | ((unsigned long long)f2bf(v.y) << 16)
                        | ((unsigned long long)f2bf(v.z) << 32)
                        | ((unsigned long long)f2bf(v.w) << 48);
  *(unsigned long long*)(Abf + (size_t)wid * 256 + lane * 4) = pk;
  float s = v.x + v.y + v.z + v.w;   // integer-valued: any order exact
  #pragma unroll
  for (int o = 32; o > 0; o >>= 1) s += __shfl_down(s, o);
  if (lane == 0) dinv[wid] = 1.0f / sqrtf(s + 2.0f);
}

// ---------- dinv from bf16 integer adjacency (exact) ----------
__global__ __launch_bounds__(256) void k_dinv_bf(const unsigned short* __restrict__ Abf,
                                                 float* __restrict__ dinv, int n, int rows) {
  int wid = (blockIdx.x * 256 + threadIdx.x) >> 6;
  int lane = threadIdx.x & 63;
  if (wid >= rows) return;
  const unsigned short* row = Abf + (size_t)wid * n;
  float s = 0.f;
  for (int j = lane * 2; j < n; j += 128) {
    unsigned u = *(const unsigned*)(row + j);
    s += bf2f((unsigned short)(u & 0xffffu)) + bf2f((unsigned short)(u >> 16));
  }
  #pragma unroll
  for (int o = 32; o > 0; o >>= 1) s += __shfl_down(s, o);
  if (lane == 0) dinv[wid] = 1.0f / sqrtf(s + 2.0f);
}

// ---------- rowsum -> dinv (fp32 A, deeper levels; integer values -> exact) ----------
__global__ __launch_bounds__(256) void k_dinv(const float* __restrict__ A,
                                              float* __restrict__ dinv,
                                              int n, int rows) {
  int wid  = (blockIdx.x * blockDim.x + threadIdx.x) >> 6;
  int lane = threadIdx.x & 63;
  if (wid >= rows) return;
  const float* row = A + (size_t)wid * n;
  float s = 0.f;
  for (int j = lane; j < n; j += 64) s += row[j];
  #pragma unroll
  for (int o = 32; o > 0; o >>= 1) s += __shfl_down(s, o);
  if (lane == 0) dinv[wid] = 1.0f / sqrtf(s + 2.0f);
}

// ---------- XW = H @ W, 4x4 register blocking, serial-k order (bit-identical) ----------
// block: 64 rows; LDS: sW[K][FP] (FP=4*FG) + sH[64][K+1]
__global__ __launch_bounds__(256) void k_xw2(const float* __restrict__ H,
                                             const float* __restrict__ W,
                                             float* __restrict__ XW,
                                             int rowsTotal, int K, int F, int FG) {
  extern __shared__ float fsm[];
  int FP = FG * 4;
  float* sW = fsm;
  float* sH = fsm + (size_t)K * FP;
  int t = threadIdx.x;
  for (int i = t; i < K * FP; i += 256) {
    int kk = i / FP, f = i - kk * FP;
    sW[i] = (f < F) ? W[kk * F + f] : 0.f;
  }
  long row0 = (long)blockIdx.x * 64;
  int nrows = min(64, rowsTotal - (int)row0);
  for (int i = t; i < nrows * K; i += 256) {
    int r = i / K, c = i - r * K;
    sH[r * (K + 1) + c] = H[row0 * K + i];
  }
  __syncthreads();
  int items = 16 * FG;
  for (int it = t; it < items; it += 256) {
    int rg = it / FG, fg = it - rg * FG;
    if (rg * 4 >= nrows) continue;
    float acc[4][4] = {};
    const float* h0 = &sH[(rg * 4) * (K + 1)];
    for (int kk = 0; kk < K; kk++) {
      float4 w = *(const float4*)&sW[kk * FP + fg * 4];
      float a0 = h0[kk], a1 = h0[(K + 1) + kk], a2 = h0[2 * (K + 1) + kk], a3 = h0[3 * (K + 1) + kk];
      acc[0][0] += a0 * w.x; acc[0][1] += a0 * w.y; acc[0][2] += a0 * w.z; acc[0][3] += a0 * w.w;
      acc[1][0] += a1 * w.x; acc[1][1] += a1 * w.y; acc[1][2] += a1 * w.z; acc[1][3] += a1 * w.w;
      acc[2][0] += a2 * w.x; acc[2][1] += a2 * w.y; acc[2][2] += a2 * w.z; acc[2][3] += a2 * w.w;
      acc[3][0] += a3 * w.x; acc[3][1] += a3 * w.y; acc[3][2] += a3 * w.z; acc[3][3] += a3 * w.w;
    }
    #pragma unroll
    for (int rr = 0; rr < 4; rr++) {
      int r = rg * 4 + rr;
      if (r < nrows) {
        #pragma unroll
        for (int ff = 0; ff < 4; ff++) {
          int f = fg * 4 + ff;
          if (f < F) XW[(row0 + r) * F + f] = acc[rr][ff];
        }
      }
    }
  }
}

// ---------- fused GCN: build split-bf16 Y in LDS, A frags held in regs, MFMA ----------
// out[b,i,f] = relu?( d_i*(A@(Yh+Yl)) + 2 d_i^2 xw_if + bias_f );  Y[f][j]=d_j*xw[j][f]
// Template KS: n = KS*32. One block = (batch, it-range). F chunked [f0, f0+FH).
template<int KS>
__global__ __launch_bounds__(256) void k_gcn(
    const unsigned short* __restrict__ Abf, const float* __restrict__ dinv,
    const float* __restrict__ xw, const float* __restrict__ bias,
    float* __restrict__ out,
    int F, int f0, int FH, int bpb, int itPW, int dorelu) {
  constexpr int n = KS * 32;
  extern __shared__ unsigned short smem[];
  unsigned short* Yh = smem;
  unsigned short* Yl = smem + (size_t)FH * n;
  int b = blockIdx.x / bpb;
  int sub = blockIdx.x - b * bpb;
  int t = threadIdx.x;
  const float* dv = dinv + (size_t)b * n;
  int FV = F - f0;           // valid cols in this chunk (may be < FH)
  // ---- build Y in LDS (XOR-swizzled 8-elem chunks for bank-friendly b128 reads) ----
  for (int idx = t; idx < FH * n; idx += 256) {
    int j = idx / FH;
    int fl = idx - j * FH;
    float v = 0.f;
    if (fl < FV) v = dv[j] * xw[((size_t)b * n + j) * F + (f0 + fl)];
    unsigned short hi = f2bf(v);
    unsigned short lo = f2bf(v - bf2f(hi));
    int c = j >> 3, e = j & 7;
    int jj = (((c ^ (fl & 7)) << 3) + e);
    Yh[fl * n + jj] = hi;
    Yl[fl * n + jj] = lo;
  }
  __syncthreads();
  // ---- MFMA tiles ----
  int wave = t >> 6, lane = t & 63;
  int r = lane & 15, q = lane >> 4;
  int nIT = n >> 4, nFT = FH >> 4;
  int itBase = sub * (nIT / bpb) + wave * itPW;
  for (int itl = 0; itl < itPW; itl++) {
    int it = itBase + itl;
    const unsigned short* ap = Abf + ((size_t)b * n + it * 16 + r) * n + q * 8;
    bf16x8_t af[KS];
    #pragma unroll
    for (int ks = 0; ks < KS; ks++) af[ks] = *(const bf16x8_t*)(ap + ks * 32);
    for (int ft = 0; ft < nFT; ft++) {
      int fl = ft * 16 + r;
      int s = fl & 7;
      f32x4_t acc = {0.f, 0.f, 0.f, 0.f};
      #pragma unroll
      for (int ks = 0; ks < KS; ks++) {
        int cs = ((ks * 4 + q) ^ s) << 3;
        bf16x8_t bh = *(const bf16x8_t*)&Yh[fl * n + cs];
        bf16x8_t bl = *(const bf16x8_t*)&Yl[fl * n + cs];
        acc = __builtin_amdgcn_mfma_f32_16x16x32_bf16(af[ks], bh, acc, 0, 0, 0);
        acc = __builtin_amdgcn_mfma_f32_16x16x32_bf16(af[ks], bl, acc, 0, 0, 0);
      }
      int f = f0 + fl;
      if (f < F) {
        #pragma unroll
        for (int reg = 0; reg < 4; reg++) {
          int i = it * 16 + q * 4 + reg;
          float di = dv[i];
          float xv = xw[((size_t)b * n + i) * F + f];
          float v = di * acc[reg] + 2.f * di * di * xv + bias[f];
          if (dorelu) v = fmaxf(v, 0.f);
          out[((size_t)b * n + i) * F + f] = v;
        }
      }
    }
  }
}

// ---------- MFMA augment (EXACT integer arithmetic) ----------
__global__ __launch_bounds__(256) void k_aug_mfma(const unsigned short* __restrict__ Abf,
                                                  const int* __restrict__ perm,
                                                  float* __restrict__ Ap,
                                                  unsigned short* __restrict__ Apbf,
                                                  int n, int k, int nTiles) {
  int wid = (blockIdx.x * 256 + threadIdx.x) >> 6;
  if (wid >= nTiles) return;
  int lane = threadIdx.x & 63;
  int kt = k >> 4;
  int b = wid / (kt * kt);
  int rem = wid - b * (kt * kt);
  int it = rem / kt, ft = rem - it * kt;
  int r = lane & 15, q = lane >> 4;
  const int* pm = perm + (size_t)b * k;
  int rowA = pm[it * 16 + r];
  int rowB = pm[ft * 16 + r];
  const unsigned short* Ab = Abf + (size_t)b * n * n;
  const unsigned short* pa = Ab + (size_t)rowA * n + q * 8;
  const unsigned short* pb = Ab + (size_t)rowB * n + q * 8;
  f32x4_t acc = {0.f, 0.f, 0.f, 0.f};
  for (int k0 = 0; k0 < n; k0 += 32) {
    bf16x8_t a  = *(const bf16x8_t*)(pa + k0);
    bf16x8_t bv = *(const bf16x8_t*)(pb + k0);
    acc = __builtin_amdgcn_mfma_f32_16x16x32_bf16(a, bv, acc, 0, 0, 0);
  }
  int c = ft * 16 + r;
  const unsigned short* rowBp = Ab + (size_t)rowB * n;
  #pragma unroll
  for (int reg = 0; reg < 4; reg++) {
    int rr = it * 16 + q * 4 + reg;
    int pr = pm[rr];
    float v = acc[reg] + 2.f * bf2f(rowBp[pr]);
    if (rr == c) v = 0.f;
    if (Ap)   Ap[((size_t)b * k + rr) * k + c] = v;
    if (Apbf) Apbf[((size_t)b * k + rr) * k + c] = f2bf(v);
  }
}

// ---------- VALU augment for tiny levels ----------
__global__ __launch_bounds__(256) void k_aug(const float* __restrict__ A,
                                             const int* __restrict__ perm,
                                             float* __restrict__ Ap,
                                             int n, int k) {
  int b = blockIdx.y, r0 = blockIdx.x * 4, t = threadIdx.x;
  __shared__ float sR[4 * 256];
  __shared__ int spm[4];
  const float* Ab = A + (size_t)b * n * n;
  if (t < 4) spm[t] = perm[(size_t)b * k + r0 + t];
  __syncthreads();
  for (int idx = t; idx < 4 * n; idx += 256) {
    int rl = idx / n, j = idx - rl * n;
    sR[rl * n + j] = Ab[(size_t)spm[rl] * n + j];
  }
  __syncthreads();
  for (int c = t; c < k; c += 256) {
    int pc = perm[(size_t)b * k + c];
    const float* rowc = Ab + (size_t)pc * n;
    float a0 = 0.f, a1 = 0.f, a2 = 0.f, a3 = 0.f;
    for (int j = 0; j < n; j++) {
      float v = rowc[j];
      a0 += sR[j] * v;
      a1 += sR[n + j] * v;
      a2 += sR[2 * n + j] * v;
      a3 += sR[3 * n + j] * v;
    }
    float accs[4] = {a0, a1, a2, a3};
    for (int rl = 0; rl < 4; rl++) {
      int r = r0 + rl;
      float res = accs[rl] + 2.f * Ab[(size_t)spm[rl] * n + pc];
      Ap[((size_t)b * k + r) * k + c] = (r == c) ? 0.f : res;
    }
  }
}

// ---------- VALU anxw for small n ----------
__global__ __launch_bounds__(256) void k_anxw(const float* __restrict__ A,
                                              const float* __restrict__ dinv,
                                              const float* __restrict__ xw,
                                              const float* __restrict__ bias,
                                              float* __restrict__ out,
                                              int n, int F, int dorelu) {
  int b = blockIdx.y, i0 = blockIdx.x * 4, t = threadIdx.x;
  __shared__ float sA[4 * 256];
  const float* Ab = A + (size_t)b * n * n;
  const float* dv = dinv + (size_t)b * n;
  for (int idx = t; idx < 4 * n; idx += 256) {
    int il = idx / n, j = idx - il * n;
    sA[il * n + j] = Ab[(size_t)(i0 + il) * n + j] * dv[j];
  }
  __syncthreads();
  const float* xwb = xw + (size_t)b * n * F;
  for (int idx = t; idx < 4 * F; idx += 256) {
    int il = idx / F, f = idx - il * F;
    int i = i0 + il;
    const float* sr = &sA[il * n];
    float acc = 0.f;
    for (int j = 0; j < n; j++) acc += sr[j] * xwb[(size_t)j * F + f];
    float di = dv[i];
    float v = di * acc + 2.f * di * di * xwb[(size_t)i * F + f] + bias[f];
    if (dorelu) v = fmaxf(v, 0.f);
    out[((size_t)b * n + i) * F + f] = v;
  }
}

// ---------- fused pooling: score + exact top-k rank + gather ----------
__global__ __launch_bounds__(256) void k_pool(const float* __restrict__ H,
                                              const float* __restrict__ p,
                                              int* __restrict__ perm,
                                              float* __restrict__ Hout,
                                              int n, int k) {
  int b = blockIdx.x, t = threadIdx.x;
  __shared__ float s[256];
  __shared__ int sord[128];
  float pn = 0.f;
  #pragma unroll
  for (int j = 0; j < HID; j++) pn += p[j] * p[j];
  if (t < n) {
    const float* hr = H + ((size_t)b * n + t) * HID;
    float acc = 0.f;
    #pragma unroll
    for (int j = 0; j < HID; j++) acc += hr[j] * p[j];
    s[t] = tanhf(acc / sqrtf(pn));
  }
  __syncthreads();
  if (t < n) {
    float v = s[t];
    int r = 0;
    for (int j = 0; j < n; j++) {
      float u = s[j];
      r += (u > v) || (u == v && j < t);
    }
    if (r < k) { perm[(size_t)b * k + r] = t; sord[r] = t; }
  }
  __syncthreads();
  for (int idx = t; idx < k * HID; idx += 256) {
    int r = idx / HID, f = idx - r * HID;
    int pi = sord[r];
    Hout[((size_t)b * k + r) * HID + f] = H[((size_t)b * n + pi) * HID + f] * s[pi];
  }
}

// ---------- decoder scatter-add ----------
__global__ __launch_bounds__(256) void k_scatter(const int* __restrict__ perm,
                                                 const float* __restrict__ Hsrc,
                                                 float* __restrict__ Hdst,
                                                 int n, int k, int total) {
  int idx = blockIdx.x * 256 + threadIdx.x;
  if (idx >= total) return;
  int f = idx % HID;
  int r = (idx / HID) % k;
  int b = idx / (HID * k);
  int pi = perm[(size_t)b * k + r];
  Hdst[((size_t)b * n + pi) * HID + f] += Hsrc[idx];
}

// ---------- fused head ----------
__global__ __launch_bounds__(256) void k_head(const float* __restrict__ HT,
                                              const float* __restrict__ c1W,
                                              const float* __restrict__ c1b,
                                              const float* __restrict__ c2W,
                                              const float* __restrict__ c2b,
                                              const float* __restrict__ oW,
                                              const float* __restrict__ ob,
                                              float* __restrict__ out) {
  int b = blockIdx.x, t = threadIdx.x;
  __shared__ float sc[256];
  __shared__ int ord[30];
  __shared__ float sp[30 * 97];
  __shared__ float y1[16 * 30];
  __shared__ float yp[16 * 15];
  __shared__ float yc[32 * 11];
  const float* Hb = HT + (size_t)b * NNODE * DOUT;
  sc[t] = Hb[(size_t)t * DOUT + (DOUT - 1)];
  __syncthreads();
  {
    float v = sc[t];
    int r = 0;
    for (int j = 0; j < 256; j++) {
      float u = sc[j];
      r += (u > v) || (u == v && j < t);
    }
    if (r < 30) ord[r] = t;
  }
  __syncthreads();
  for (int idx = t; idx < 30 * 97; idx += 256) {
    int r = idx / 97, d = idx - r * 97;
    sp[idx] = Hb[(size_t)ord[r] * DOUT + d];
  }
  __syncthreads();
  for (int idx = t; idx < 16 * 30; idx += 256) {
    int c = idx / 30, kk = idx - c * 30;
    float a = c1b[c];
    for (int d = 0; d < 97; d++) a += sp[kk * 97 + d] * c1W[c * 97 + d];
    y1[c * 30 + kk] = fmaxf(a, 0.f);
  }
  __syncthreads();
  for (int idx = t; idx < 16 * 15; idx += 256) {
    int c = idx / 15, t2 = idx - c * 15;
    yp[idx] = fmaxf(y1[c * 30 + 2 * t2], y1[c * 30 + 2 * t2 + 1]);
  }
  __syncthreads();
  for (int idx = t; idx < 32 * 11; idx += 256) {
    int o = idx / 11, t3 = idx - o * 11;
    float a = c2b[o];
    for (int i2 = 0; i2 < 16; i2++)
      for (int w = 0; w < 5; w++)
        a += yp[i2 * 15 + t3 + w] * c2W[(o * 16 + i2) * 5 + w];
    yc[o * 11 + t3] = fmaxf(a, 0.f);
  }
  __syncthreads();
  if (t < 32) {
    float a = ob[t];
    for (int q = 0; q < 352; q++) a += yc[q] * oW[q * 32 + t];
    out[(size_t)b * 32 + t] = fmaxf(a, 0.f);
  }
}

extern "C" void kernel_launch(void* const* d_in, const int* in_sizes, int n_in,
                              void* d_out, int out_size, void* d_ws, size_t ws_size,
                              hipStream_t stream) {
  const float* x   = (const float*)d_in[0];
  const float* A0  = (const float*)d_in[1];
  const float* dW0 = (const float*)d_in[2];
  const float* db0 = (const float*)d_in[3];
  const float* dW  = (const float*)d_in[4];
  const float* dbv = (const float*)d_in[5];
  const float* pp  = (const float*)d_in[6];
  const float* uW  = (const float*)d_in[7];
  const float* ub  = (const float*)d_in[8];
  const float* uWl = (const float*)d_in[9];
  const float* ubl = (const float*)d_in[10];
  const float* c1W = (const float*)d_in[11];
  const float* c1b = (const float*)d_in[12];
  const float* c2W = (const float*)d_in[13];
  const float* c2b = (const float*)d_in[14];
  const float* oW  = (const float*)d_in[15];
  const float* ob  = (const float*)d_in[16];
  float* out = (float*)d_out;

  float* base = (float*)d_ws;
  size_t off = 0;
  auto alloc = [&](size_t nel) { nel = (nel + 3) & ~(size_t)3; float* p = base + off; off += nel; return p; };
  float* H0 = alloc((size_t)BATCH * 256 * HID);
  float* H1 = alloc((size_t)BATCH * 128 * HID);
  float* H2 = alloc((size_t)BATCH * 64 * HID);
  float* H3 = alloc((size_t)BATCH * 32 * HID);
  float* H4 = alloc((size_t)BATCH * 16 * HID);
  float* HT = alloc((size_t)BATCH * 256 * DOUT);
  float* XW = alloc((size_t)BATCH * 256 * DOUT);
  float* A2 = alloc((size_t)BATCH * 64 * 64);
  float* A3 = alloc((size_t)BATCH * 32 * 32);
  float* A4 = alloc((size_t)BATCH * 16 * 16);
  float* D0 = alloc((size_t)BATCH * 256);
  float* D1 = alloc((size_t)BATCH * 128);
  float* D2 = alloc((size_t)BATCH * 64);
  float* D3 = alloc((size_t)BATCH * 32);
  float* D4 = alloc((size_t)BATCH * 16);
  int* P1 = (int*)alloc((size_t)BATCH * 128);
  int* P2 = (int*)alloc((size_t)BATCH * 64);
  int* P3 = (int*)alloc((size_t)BATCH * 32);
  int* P4 = (int*)alloc((size_t)BATCH * 16);
  unsigned short* Abf0 = (unsigned short*)alloc((size_t)BATCH * 256 * 256 / 2);
  unsigned short* Abf1 = (unsigned short*)alloc((size_t)BATCH * 128 * 128 / 2);

  int ns[5] = {256, 128, 64, 32, 16};
  float* Hl[5] = {H0, H1, H2, H3, H4};
  float* Al[5] = {nullptr, nullptr, A2, A3, A4};
  float* Dl[5] = {D0, D1, D2, D3, D4};
  int* Pl[4] = {P1, P2, P3, P4};

  // ---- prologue: A0 -> bf16 + dinv in one pass ----
  k_prepA<<<BATCH * 256 / 4, 256, 0, stream>>>(A0, Abf0, D0, BATCH * 256);

  // ---- first GCN ----
  {
    int shm = FIN * 48 * 4 + 64 * (FIN + 1) * 4;          // 57600
    k_xw2<<<BATCH * 256 / 64, 256, shm, stream>>>(x, dW0, XW, BATCH * 256, FIN, HID, 12);
    int shg = 48 * 256 * 2 * 2;                           // 49152
    k_gcn<8><<<BATCH * 2, 256, shg, stream>>>(Abf0, D0, XW, db0, H0, HID, 0, 48, 2, 2, 1);
  }

  int shxw48 = 48 * 48 * 4 + 64 * 49 * 4;                 // 21760
  int shg128 = 48 * 128 * 2 * 2;                          // 24576

  // ---- encoder levels ----
  for (int i = 0; i < 4; i++) {
    int n = ns[i], kk = ns[i + 1];
    k_pool<<<BATCH, 256, 0, stream>>>(Hl[i], pp + i * HID, Pl[i], Hl[i + 1], n, kk);
    if (i == 0) {
      int nT = BATCH * 8 * 8;
      k_aug_mfma<<<(nT + 3) / 4, 256, 0, stream>>>(Abf0, P1, nullptr, Abf1, 256, 128, nT);
      k_dinv_bf<<<BATCH * 128 / 4, 256, 0, stream>>>(Abf1, D1, 128, BATCH * 128);
    } else if (i == 1) {
      int nT = BATCH * 4 * 4;
      k_aug_mfma<<<(nT + 3) / 4, 256, 0, stream>>>(Abf1, P2, A2, nullptr, 128, 64, nT);
      k_dinv<<<BATCH * 64 / 4, 256, 0, stream>>>(A2, D2, 64, BATCH * 64);
    } else {
      k_aug<<<dim3(kk / 4, BATCH), 256, 0, stream>>>(Al[i], Pl[i], Al[i + 1], n, kk);
      k_dinv<<<(BATCH * kk + 3) / 4, 256, 0, stream>>>(Al[i + 1], Dl[i + 1], kk, BATCH * kk);
    }
    k_xw2<<<(BATCH * kk + 63) / 64, 256, shxw48, stream>>>(Hl[i + 1], dW + (size_t)i * HID * HID,
                                                           XW, BATCH * kk, HID, HID, 12);
    if (kk == 128) {
      k_gcn<4><<<BATCH * 2, 256, shg128, stream>>>(Abf1, D1, XW, dbv + i * HID, Hl[i + 1],
                                                   HID, 0, 48, 2, 1, 1);
    } else {
      k_anxw<<<dim3(kk / 4, BATCH), 256, 0, stream>>>(Al[i + 1], Dl[i + 1], XW,
                                                      dbv + i * HID, Hl[i + 1], kk, HID, 1);
    }
  }

  // ---- decoder ----
  for (int i = 0; i < 4; i++) {
    int j = 3 - i, nj = ns[j], kj = ns[j + 1];
    k_scatter<<<(BATCH * kj * HID + 255) / 256, 256, 0, stream>>>(Pl[j], Hl[j + 1], Hl[j],
                                                                  nj, kj, BATCH * kj * HID);
    if (i < 3) {
      k_xw2<<<(BATCH * nj + 63) / 64, 256, shxw48, stream>>>(Hl[j], uW + (size_t)i * HID * HID,
                                                             XW, BATCH * nj, HID, HID, 12);
      if (nj == 128) {
        k_gcn<4><<<BATCH * 2, 256, shg128, stream>>>(Abf1, D1, XW, ub + i * HID, Hl[j],
                                                     HID, 0, 48, 2, 1, 1);
      } else {
        k_anxw<<<dim3(nj / 4, BATCH), 256, 0, stream>>>(Al[j], Dl[j], XW, ub + i * HID,
                                                        Hl[j], nj, HID, 1);
      }
    } else {
      int shm = 48 * 100 * 4 + 64 * 49 * 4;               // 31744
      k_xw2<<<BATCH * 256 / 64, 256, shm, stream>>>(H0, uWl, XW, BATCH * 256, HID, DOUT, 25);
      int shg0 = 64 * 256 * 2 * 2;                        // 65536
      int shg1 = 48 * 256 * 2 * 2;                        // 49152
      k_gcn<8><<<BATCH * 2, 256, shg0, stream>>>(Abf0, D0, XW, ubl, HT, DOUT, 0, 64, 2, 2, 0);
      k_gcn<8><<<BATCH * 2, 256, shg1, stream>>>(Abf0, D0, XW, ubl, HT, DOUT, 64, 48, 2, 2, 0);
    }
  }

  // ---- fused head ----
  k_head<<<BATCH, 256, 0, stream>>>(HT, c1W, c1b, c2W, c2b, oW, ob, out);
}